// Round 5
// baseline (2328.124 us; speedup 1.0000x reference)
//
#include <hip/hip_runtime.h>
#include <hip/hip_bf16.h>
#include <math.h>

#define L_  12
#define H_  12
#define D_  768
#define FF_ 3072
#define V_  32000
#define T_  1024
#define B_  2
#define BT_ (B_*T_)

typedef unsigned short ushort_t;
typedef unsigned int   uint_t;
typedef __bf16 bf16x8 __attribute__((ext_vector_type(8)));
typedef float  f32x4  __attribute__((ext_vector_type(4)));

__device__ __forceinline__ uint_t f2bf1(float f) {
    uint_t u = __builtin_bit_cast(uint_t, f);
    return (u + 0x7FFFu + ((u >> 16) & 1u)) >> 16;   // RNE truncate to bf16
}
__device__ __forceinline__ uint_t f2bf2(float lo, float hi) {
    return f2bf1(lo) | (f2bf1(hi) << 16);
}

__device__ __forceinline__ void gl_lds16(const ushort_t* g, ushort_t* l) {
    __builtin_amdgcn_global_load_lds(
        (const __attribute__((address_space(1))) uint_t*)g,
        (__attribute__((address_space(3))) uint_t*)l, 16, 0, 0);
}

// ---------------- weight cast kernels ----------------
__global__ __launch_bounds__(256) void cast_bf16(const float* __restrict__ in,
                                                 ushort_t* __restrict__ out, int n8)
{
    for (int i = blockIdx.x * 256 + threadIdx.x; i < n8; i += gridDim.x * 256) {
        const float4* p = (const float4*)(in + (size_t)i * 8);
        float4 a = p[0], b = p[1];
        *(uint4*)(out + (size_t)i * 8) =
            make_uint4(f2bf2(a.x,a.y), f2bf2(a.z,a.w), f2bf2(b.x,b.y), f2bf2(b.z,b.w));
    }
}

// one layer's {qkv_w, out_w, up_w, down_w} -> contiguous bf16 buffer
__global__ __launch_bounds__(256) void cast_layer(const float* __restrict__ q,
    const float* __restrict__ o, const float* __restrict__ u, const float* __restrict__ d,
    ushort_t* __restrict__ out)
{
    const int N0 = 3*D_*D_/8, N1 = N0 + D_*D_/8, N2 = N1 + FF_*D_/8, N3 = N2 + D_*FF_/8;
    for (int i = blockIdx.x * 256 + threadIdx.x; i < N3; i += gridDim.x * 256) {
        const float* src;
        if      (i < N0) src = q + (size_t)i * 8;
        else if (i < N1) src = o + (size_t)(i - N0) * 8;
        else if (i < N2) src = u + (size_t)(i - N1) * 8;
        else             src = d + (size_t)(i - N2) * 8;
        const float4* p = (const float4*)src;
        float4 a = p[0], b = p[1];
        *(uint4*)(out + (size_t)i * 8) =
            make_uint4(f2bf2(a.x,a.y), f2bf2(a.z,a.w), f2bf2(b.x,b.y), f2bf2(b.z,b.w));
    }
}

// ---------------- GEMM: C[M,N] = A[M,K] @ W[N,K]^T (+R), bf16, BK=64, dbuf prefetch ----------------
#define EPI_F32   0
#define EPI_BF16  1
#define EPI_GELU  2
#define EPI_RES   3

template <int EPI, int BM>
__global__ __launch_bounds__(256) void gemm_bt(
    const ushort_t* __restrict__ A, const ushort_t* __restrict__ W,
    const float* R, void* Cv, int N, int K)
{
    constexpr int MI = BM / 32;          // A-fragment tiles per wave
    constexpr int AH = BM * 64;          // ushorts per A buffer
    constexpr int BH = 128 * 64;
    __shared__ ushort_t As[2 * AH];      // linear dest (global_load_lds); content chunk-swizzled
    __shared__ ushort_t Bs[2 * BH];

    const int tid  = threadIdx.x;
    const int w    = tid >> 6;
    const int lane = tid & 63;

    // XCD-aware swizzle (nwg % 8 == 0 for all our shapes), M-fastest decode
    const int nwg = gridDim.x;
    int swz = (blockIdx.x & 7) * (nwg >> 3) + (blockIdx.x >> 3);
    constexpr int MT = 2048 / BM;
    const int mt = swz & (MT - 1);
    const int nt = swz / MT;
    const int m0 = mt * BM, n0 = nt * 128;

    // staging: source col chunk XOR'd with (ldsrow & 7) so the LINEAR lds write lands swizzled
    const int srow = lane >> 3;                       // 0..7
    const int scol = ((lane & 7) ^ srow) * 8;         // inverse-swizzled global chunk
    const ushort_t* gA = A + (size_t)(m0 + w * (BM / 4) + srow) * K + scol;
    const ushort_t* gW = W + (size_t)(n0 + w * 32 + srow) * K + scol;
    const size_t row8 = (size_t)8 * K;

    const int lr = lane & 15;
    const int lg = lane >> 4;
    const int wm = (w >> 1) * (BM / 2);
    const int wn = (w & 1) * 64;

    f32x4 acc[MI][4] = {};

    auto stage = [&](int buf, int k0) {
        ushort_t* lA = As + buf * AH + w * (BM / 4) * 64;
        ushort_t* lB = Bs + buf * BH + w * 2048;
        #pragma unroll
        for (int i = 0; i < BM / 32; ++i)
            gl_lds16(gA + k0 + i * row8, lA + i * 512);
        #pragma unroll
        for (int i = 0; i < 4; ++i)
            gl_lds16(gW + k0 + i * row8, lB + i * 512);
    };

    stage(0, 0);
    __syncthreads();
    int cur = 0;
    for (int k0 = 0; k0 < K; k0 += 64) {
        if (k0 + 64 < K) stage(cur ^ 1, k0 + 64);     // prefetch flies under MFMA below
        const ushort_t* Ab = As + cur * AH;
        const ushort_t* Bb = Bs + cur * BH;
        __builtin_amdgcn_s_setprio(1);
        #pragma unroll
        for (int kk = 0; kk < 2; ++kk) {
            bf16x8 av[MI], bv[4];
            #pragma unroll
            for (int i = 0; i < MI; ++i) {
                int rr = wm + i * 16 + lr;
                int ch = (lg + 4 * kk) ^ (rr & 7);
                av[i] = *(const bf16x8*)&Ab[rr * 64 + ch * 8];
            }
            #pragma unroll
            for (int j = 0; j < 4; ++j) {
                int rr = wn + j * 16 + lr;
                int ch = (lg + 4 * kk) ^ (rr & 7);
                bv[j] = *(const bf16x8*)&Bb[rr * 64 + ch * 8];
            }
            #pragma unroll
            for (int i = 0; i < MI; ++i)
                #pragma unroll
                for (int j = 0; j < 4; ++j)
                    acc[i][j] = __builtin_amdgcn_mfma_f32_16x16x32_bf16(av[i], bv[j], acc[i][j], 0, 0, 0);
        }
        __builtin_amdgcn_s_setprio(0);
        __syncthreads();                               // drains prefetch + ends read phase
        cur ^= 1;
    }

    float*    Cf = (float*)Cv;
    ushort_t* Cb = (ushort_t*)Cv;
    const int rbase = lg * 4;
    #pragma unroll
    for (int i = 0; i < MI; ++i) {
        #pragma unroll
        for (int j = 0; j < 4; ++j) {
            #pragma unroll
            for (int r = 0; r < 4; ++r) {
                int row = m0 + wm + i * 16 + rbase + r;
                int col = n0 + wn + j * 16 + lr;
                size_t idx = (size_t)row * N + col;
                float v = acc[i][j][r];
                if (EPI == EPI_F32)  Cf[idx] = v;
                if (EPI == EPI_BF16) Cb[idx] = (ushort_t)f2bf1(v);
                if (EPI == EPI_GELU) Cb[idx] = (ushort_t)f2bf1(0.5f * v * (1.0f + erff(v * 0.70710678118654752f)));
                if (EPI == EPI_RES)  Cf[idx] = R[idx] + v;   // one writer per element, no race
            }
        }
    }
}

// ---------------- V transpose: qkv bf16 V-slice -> vt[bh][64][T] ----------------
__global__ __launch_bounds__(256) void vprep(const ushort_t* __restrict__ qkv,
                                             ushort_t* __restrict__ vt)
{
    __shared__ ushort_t Vs[64][72];
    const int blk   = blockIdx.x;
    const int ttile = blk & 15;
    const int bh    = blk >> 4;
    const int b     = bh / H_;
    const int h     = bh % H_;
    const int tid   = threadIdx.x;
    const int t0    = ttile * 64;
    {
        const int tr = tid >> 2;
        const int dc = (tid & 3) * 16;
        const uint4* src = (const uint4*)(qkv + (size_t)(b * T_ + t0 + tr) * 2304 + 1536 + h * 64 + dc);
        uint4 v0 = src[0], v1 = src[1];
        *(uint4*)&Vs[tr][dc]     = v0;
        *(uint4*)&Vs[tr][dc + 8] = v1;
    }
    __syncthreads();
    {
        const int d  = tid >> 2;
        const int jc = (tid & 3) * 16;
        uint_t w[8];
        #pragma unroll
        for (int i = 0; i < 8; ++i)
            w[i] = (uint_t)Vs[jc + 2*i][d] | ((uint_t)Vs[jc + 2*i + 1][d] << 16);
        uint4* dst = (uint4*)(vt + ((size_t)bh * 64 + d) * T_ + t0 + jc);
        dst[0] = make_uint4(w[0], w[1], w[2], w[3]);
        dst[1] = make_uint4(w[4], w[5], w[6], w[7]);
    }
}

// ---------------- MFMA flash attention, no-LDS K/V (L2-resident), 1 wave / 16 q-rows ----------------
__global__ __launch_bounds__(64) void attn_mfma(const ushort_t* __restrict__ qkv,
    const ushort_t* __restrict__ vt, ushort_t* __restrict__ o)
{
    __shared__ ushort_t Ps[16 * 136];

    // bh-clustered XCD swizzle: 1536 blocks -> 8 chunks of 192 (3 bh each)
    int swz = (blockIdx.x & 7) * 192 + (blockIdx.x >> 3);
    const int bh  = swz >> 6;
    const int qtl = 63 - (swz & 63);     // heavy q-tiles first within chunk
    const int b   = bh / H_;
    const int h   = bh % H_;
    const int lane = threadIdx.x;
    const int l15  = lane & 15;
    const int lg   = lane >> 4;
    const int qbase = qtl * 16;
    const int qlast = qbase + 15;

    const ushort_t* qp = qkv + ((size_t)(b * T_) + qbase + l15) * 2304 + h * 64 + lg * 8;
    bf16x8 qf0 = *(const bf16x8*)qp;
    bf16x8 qf1 = *(const bf16x8*)(qp + 32);

    f32x4 od[4] = {};
    float mr[4] = {-INFINITY, -INFINITY, -INFINITY, -INFINITY};
    float lr[4] = {0.f, 0.f, 0.f, 0.f};

    const ushort_t* kbase = qkv + (size_t)(b * T_) * 2304 + 768 + h * 64;
    const ushort_t* vbase = vt + (size_t)bh * 64 * T_;
    const float SC = 0.18033688011112042f;   // 0.125 * log2(e): softmax in exp2 domain

    for (int j0 = 0; j0 <= qlast; j0 += 128) {
        f32x4 s[8];
        __builtin_amdgcn_s_setprio(1);
        #pragma unroll
        for (int n = 0; n < 8; ++n) {
            if (j0 + 16 * n <= qlast) {
                const ushort_t* kr = kbase + (size_t)(j0 + 16 * n + l15) * 2304 + lg * 8;
                bf16x8 kf0 = *(const bf16x8*)kr;
                bf16x8 kf1 = *(const bf16x8*)(kr + 32);
                f32x4 a = {};
                a = __builtin_amdgcn_mfma_f32_16x16x32_bf16(qf0, kf0, a, 0, 0, 0);
                a = __builtin_amdgcn_mfma_f32_16x16x32_bf16(qf1, kf1, a, 0, 0, 0);
                s[n] = a;
            } else {
                s[n] = f32x4{-INFINITY, -INFINITY, -INFINITY, -INFINITY};
            }
        }
        __builtin_amdgcn_s_setprio(0);

        #pragma unroll
        for (int n = 0; n < 8; ++n) {
            #pragma unroll
            for (int r = 0; r < 4; ++r) {
                float v = s[n][r] * SC;
                int jg = j0 + 16 * n + l15;
                int qg = qbase + lg * 4 + r;
                if (jg > qg) v = -INFINITY;
                s[n][r] = v;
            }
        }

        float al[4];
        #pragma unroll
        for (int r = 0; r < 4; ++r) {
            float tm = fmaxf(fmaxf(fmaxf(s[0][r], s[1][r]), fmaxf(s[2][r], s[3][r])),
                             fmaxf(fmaxf(s[4][r], s[5][r]), fmaxf(s[6][r], s[7][r])));
            tm = fmaxf(tm, __shfl_xor(tm, 1, 64));
            tm = fmaxf(tm, __shfl_xor(tm, 2, 64));
            tm = fmaxf(tm, __shfl_xor(tm, 4, 64));
            tm = fmaxf(tm, __shfl_xor(tm, 8, 64));
            float mn = fmaxf(mr[r], tm);
            al[r] = exp2f(mr[r] - mn);
            mr[r] = mn;
        }
        #pragma unroll
        for (int n = 0; n < 8; ++n)
            #pragma unroll
            for (int r = 0; r < 4; ++r)
                s[n][r] = exp2f(s[n][r] - mr[r]);
        #pragma unroll
        for (int r = 0; r < 4; ++r) {
            float ps = (s[0][r] + s[1][r]) + (s[2][r] + s[3][r]);
            ps += (s[4][r] + s[5][r]) + (s[6][r] + s[7][r]);
            ps += __shfl_xor(ps, 1, 64);
            ps += __shfl_xor(ps, 2, 64);
            ps += __shfl_xor(ps, 4, 64);
            ps += __shfl_xor(ps, 8, 64);
            lr[r] = lr[r] * al[r] + ps;
        }
        #pragma unroll
        for (int n = 0; n < 4; ++n)
            #pragma unroll
            for (int r = 0; r < 4; ++r)
                od[n][r] *= al[r];

        // P -> LDS rows (q = lg*4+r, j fast) for the PV A-fragment
        #pragma unroll
        for (int n = 0; n < 8; ++n)
            #pragma unroll
            for (int r = 0; r < 4; ++r)
                Ps[(lg * 4 + r) * 136 + 16 * n + l15] = (ushort_t)f2bf1(s[n][r]);

        __builtin_amdgcn_s_setprio(1);
        #pragma unroll
        for (int kc = 0; kc < 4; ++kc) {
            if (j0 + kc * 32 <= qlast) {
                bf16x8 pa = *(const bf16x8*)&Ps[l15 * 136 + kc * 32 + lg * 8];
                #pragma unroll
                for (int nn = 0; nn < 4; ++nn) {
                    bf16x8 vf = *(const bf16x8*)&vbase[(size_t)(16 * nn + l15) * T_ + j0 + kc * 32 + lg * 8];
                    od[nn] = __builtin_amdgcn_mfma_f32_16x16x32_bf16(pa, vf, od[nn], 0, 0, 0);
                }
            }
        }
        __builtin_amdgcn_s_setprio(0);
    }

    #pragma unroll
    for (int r = 0; r < 4; ++r) {
        float inv = 1.0f / lr[r];
        int row = qbase + lg * 4 + r;
        ushort_t* op = o + ((size_t)(b * T_ + row)) * 768 + h * 64 + l15;
        #pragma unroll
        for (int nn = 0; nn < 4; ++nn)
            op[16 * nn] = (ushort_t)f2bf1(od[nn][r] * inv);
    }
}

// ---------------- layernorm: fp32 in, bf16 out ----------------
__global__ __launch_bounds__(256) void ln_kernel(const float* __restrict__ x,
    const float* __restrict__ w, const float* __restrict__ bia, ushort_t* __restrict__ out)
{
    const int row = blockIdx.x;
    const int tid = threadIdx.x;
    const float* xr = x + (size_t)row * 768;
    float v0 = xr[tid], v1 = xr[tid + 256], v2 = xr[tid + 512];
    float s  = v0 + v1 + v2;
    float s2 = v0 * v0 + v1 * v1 + v2 * v2;
    #pragma unroll
    for (int off = 32; off > 0; off >>= 1) {
        s  += __shfl_down(s,  off, 64);
        s2 += __shfl_down(s2, off, 64);
    }
    __shared__ float sh[8];
    const int wave = tid >> 6;
    if ((tid & 63) == 0) { sh[wave] = s; sh[4 + wave] = s2; }
    __syncthreads();
    float S  = sh[0] + sh[1] + sh[2] + sh[3];
    float S2 = sh[4] + sh[5] + sh[6] + sh[7];
    float mean = S * (1.f / 768.f);
    float var  = S2 * (1.f / 768.f) - mean * mean;
    float inv  = rsqrtf(var + 1e-5f);
    ushort_t* orow = out + (size_t)row * 768;
    orow[tid]       = (ushort_t)f2bf1((v0 - mean) * inv * w[tid]       + bia[tid]);
    orow[tid + 256] = (ushort_t)f2bf1((v1 - mean) * inv * w[tid + 256] + bia[tid + 256]);
    orow[tid + 512] = (ushort_t)f2bf1((v2 - mean) * inv * w[tid + 512] + bia[tid + 512]);
}

// ---------------- embedding ----------------
__global__ __launch_bounds__(256) void embed_kernel(const int* __restrict__ ids,
    const float* __restrict__ tok, const float* __restrict__ pos, float* __restrict__ x)
{
    const int bt = blockIdx.x;
    const int t  = bt % T_;
    const int id = ids[bt];
    const int tid = threadIdx.x;
    const float* tr = tok + (size_t)id * 768;
    const float* pr = pos + (size_t)t * 768;
    float* xr = x + (size_t)bt * 768;
    xr[tid]       = tr[tid]       + pr[tid];
    xr[tid + 256] = tr[tid + 256] + pr[tid + 256];
    xr[tid + 512] = tr[tid + 512] + pr[tid + 512];
}

// ---------------- launcher ----------------
extern "C" void kernel_launch(void* const* d_in, const int* in_sizes, int n_in,
                              void* d_out, int out_size, void* d_ws, size_t ws_size,
                              hipStream_t stream)
{
    const int*   ids   = (const int*)  d_in[0];
    const float* tok   = (const float*)d_in[1];
    const float* pos   = (const float*)d_in[2];
    const float* ln1w  = (const float*)d_in[3];
    const float* ln1b  = (const float*)d_in[4];
    const float* qkvw  = (const float*)d_in[5];
    const float* outw  = (const float*)d_in[6];
    const float* ln2w  = (const float*)d_in[7];
    const float* ln2b  = (const float*)d_in[8];
    const float* upw   = (const float*)d_in[9];
    const float* downw = (const float*)d_in[10];
    const float* lnfw  = (const float*)d_in[11];
    const float* lnfb  = (const float*)d_in[12];
    float* out = (float*)d_out;

    // workspace (52.3 MB): h | x | qkv | o | vt | ffh | layerW ; tokW aliases x..end
    char* ws = (char*)d_ws;
    ushort_t* h    = (ushort_t*)ws;                               // 3,145,728 B
    float*    x    = (float*)   (ws + 3145728);                   // 6,291,456 B
    ushort_t* qkv  = (ushort_t*)(ws + 9437184);                   // 9,437,184 B
    ushort_t* o    = qkv  + (size_t)BT_ * 3 * D_;                 // 3,145,728 B
    ushort_t* vt   = o    + (size_t)BT_ * D_;                     // 3,145,728 B
    ushort_t* ffh  = vt   + (size_t)B_ * H_ * 64 * T_;            // 12,582,912 B
    ushort_t* layerW = ffh + (size_t)BT_ * FF_;                   // 14,155,776 B
    ushort_t* tokW = (ushort_t*)(ws + 3145728);                   // aliases x.. (49.15 MB)

    ushort_t* qkvwB  = layerW;
    ushort_t* outwB  = qkvwB + (size_t)3 * D_ * D_;
    ushort_t* upwB   = outwB + (size_t)D_ * D_;
    ushort_t* downwB = upwB  + (size_t)FF_ * D_;

    embed_kernel<<<BT_, 256, 0, stream>>>(ids, tok, pos, x);

    for (int l = 0; l < L_; ++l) {
        cast_layer<<<1024, 256, 0, stream>>>(
            qkvw  + (size_t)l * 3 * D_ * D_,
            outw  + (size_t)l * D_ * D_,
            upw   + (size_t)l * FF_ * D_,
            downw + (size_t)l * D_ * FF_, layerW);

        ln_kernel<<<BT_, 256, 0, stream>>>(x, ln1w + l * D_, ln1b + l * D_, h);

        gemm_bt<EPI_BF16, 128><<<16 * (3 * D_ / 128), 256, 0, stream>>>(
            h, qkvwB, nullptr, qkv, 3 * D_, D_);

        vprep<<<B_ * H_ * (T_ / 64), 256, 0, stream>>>(qkv, vt);
        attn_mfma<<<B_ * H_ * (T_ / 16), 64, 0, stream>>>(qkv, vt, o);

        gemm_bt<EPI_RES, 64><<<32 * (D_ / 128), 256, 0, stream>>>(
            o, outwB, x, x, D_, D_);

        ln_kernel<<<BT_, 256, 0, stream>>>(x, ln2w + l * D_, ln2b + l * D_, h);

        gemm_bt<EPI_GELU, 128><<<16 * (FF_ / 128), 256, 0, stream>>>(
            h, upwB, nullptr, ffh, FF_, D_);

        gemm_bt<EPI_RES, 64><<<32 * (D_ / 128), 256, 0, stream>>>(
            ffh, downwB, x, x, D_, FF_);
    }

    ln_kernel<<<BT_, 256, 0, stream>>>(x, lnfw, lnfb, h);
    cast_bf16<<<2048, 256, 0, stream>>>(tok, tokW, V_ * D_ / 8);
    gemm_bt<EPI_F32, 128><<<16 * (V_ / 128), 256, 0, stream>>>(
        h, tokW, nullptr, out, V_, D_);
}

// Round 6
// 2052.486 us; speedup vs baseline: 1.1343x; 1.1343x over previous
//
#include <hip/hip_runtime.h>
#include <hip/hip_bf16.h>
#include <math.h>

#define L_  12
#define H_  12
#define D_  768
#define FF_ 3072
#define V_  32000
#define T_  1024
#define B_  2
#define BT_ (B_*T_)

typedef unsigned short ushort_t;
typedef unsigned int   uint_t;
typedef __bf16 bf16x8 __attribute__((ext_vector_type(8)));
typedef float  f32x4  __attribute__((ext_vector_type(4)));

__device__ __forceinline__ uint_t f2bf1(float f) {
    uint_t u = __builtin_bit_cast(uint_t, f);
    return (u + 0x7FFFu + ((u >> 16) & 1u)) >> 16;   // RNE truncate to bf16
}
__device__ __forceinline__ uint_t f2bf2(float lo, float hi) {
    return f2bf1(lo) | (f2bf1(hi) << 16);
}

__device__ __forceinline__ void gl_lds16(const ushort_t* g, ushort_t* l) {
    __builtin_amdgcn_global_load_lds(
        (const __attribute__((address_space(1))) uint_t*)g,
        (__attribute__((address_space(3))) uint_t*)l, 16, 0, 0);
}

// ---------------- weight cast kernels ----------------
__global__ __launch_bounds__(256) void cast_bf16(const float* __restrict__ in,
                                                 ushort_t* __restrict__ out, int n8)
{
    for (int i = blockIdx.x * 256 + threadIdx.x; i < n8; i += gridDim.x * 256) {
        const float4* p = (const float4*)(in + (size_t)i * 8);
        float4 a = p[0], b = p[1];
        *(uint4*)(out + (size_t)i * 8) =
            make_uint4(f2bf2(a.x,a.y), f2bf2(a.z,a.w), f2bf2(b.x,b.y), f2bf2(b.z,b.w));
    }
}

// one layer's {qkv_w, out_w, up_w, down_w} -> contiguous bf16 buffer
__global__ __launch_bounds__(256) void cast_layer(const float* __restrict__ q,
    const float* __restrict__ o, const float* __restrict__ u, const float* __restrict__ d,
    ushort_t* __restrict__ out)
{
    const int N0 = 3*D_*D_/8, N1 = N0 + D_*D_/8, N2 = N1 + FF_*D_/8, N3 = N2 + D_*FF_/8;
    for (int i = blockIdx.x * 256 + threadIdx.x; i < N3; i += gridDim.x * 256) {
        const float* src;
        if      (i < N0) src = q + (size_t)i * 8;
        else if (i < N1) src = o + (size_t)(i - N0) * 8;
        else if (i < N2) src = u + (size_t)(i - N1) * 8;
        else             src = d + (size_t)(i - N2) * 8;
        const float4* p = (const float4*)src;
        float4 a = p[0], b = p[1];
        *(uint4*)(out + (size_t)i * 8) =
            make_uint4(f2bf2(a.x,a.y), f2bf2(a.z,a.w), f2bf2(b.x,b.y), f2bf2(b.z,b.w));
    }
}

// ---------------- GEMM: C[M,N] = A[M,K] @ W[N,K]^T, bf16, BK=64, dbuf, optional split-K ----------------
#define EPI_F32   0
#define EPI_BF16  1
#define EPI_GELU  2
#define EPI_PART  3   // split-K partials: ks==0 -> Cv, ks==1 -> R (cast away const)

template <int EPI, int BM, int KS>
__global__ __launch_bounds__(256) void gemm_bt(
    const ushort_t* __restrict__ A, const ushort_t* __restrict__ W,
    const float* R, void* Cv, int N, int K, int Kc)
{
    constexpr int MI = BM / 32;          // A-fragment tiles per wave
    constexpr int AH = BM * 64;          // ushorts per A buffer
    constexpr int BH = 128 * 64;
    __shared__ ushort_t As[2 * AH];      // linear dest (global_load_lds); content chunk-swizzled
    __shared__ ushort_t Bs[2 * BH];

    const int tid  = threadIdx.x;
    const int w    = tid >> 6;
    const int lane = tid & 63;

    // XCD-aware swizzle (nwg % 8 == 0 for all our shapes), M-fastest decode
    const int nwg = gridDim.x;
    int swz = (blockIdx.x & 7) * (nwg >> 3) + (blockIdx.x >> 3);
    constexpr int MT = 2048 / BM;
    const int mt = swz & (MT - 1);
    int rest     = swz / MT;
    const int ks = rest & (KS - 1);
    const int nt = rest / KS;
    const int m0 = mt * BM, n0 = nt * 128;
    const int kb = ks * Kc;

    // staging: source col chunk XOR'd with (ldsrow & 7) so the LINEAR lds write lands swizzled
    const int srow = lane >> 3;                       // 0..7
    const int scol = ((lane & 7) ^ srow) * 8;         // inverse-swizzled global chunk
    const ushort_t* gA = A + (size_t)(m0 + w * (BM / 4) + srow) * K + scol;
    const ushort_t* gW = W + (size_t)(n0 + w * 32 + srow) * K + scol;
    const size_t row8 = (size_t)8 * K;

    const int lr = lane & 15;
    const int lg = lane >> 4;
    const int wm = (w >> 1) * (BM / 2);
    const int wn = (w & 1) * 64;

    f32x4 acc[MI][4] = {};

    auto stage = [&](int buf, int k0) {
        ushort_t* lA = As + buf * AH + w * (BM / 4) * 64;
        ushort_t* lB = Bs + buf * BH + w * 2048;
        #pragma unroll
        for (int i = 0; i < BM / 32; ++i)
            gl_lds16(gA + k0 + i * row8, lA + i * 512);
        #pragma unroll
        for (int i = 0; i < 4; ++i)
            gl_lds16(gW + k0 + i * row8, lB + i * 512);
    };

    stage(0, kb);
    __syncthreads();
    int cur = 0;
    for (int k0 = kb; k0 < kb + Kc; k0 += 64) {
        if (k0 + 64 < kb + Kc) stage(cur ^ 1, k0 + 64);   // prefetch flies under MFMA below
        const ushort_t* Ab = As + cur * AH;
        const ushort_t* Bb = Bs + cur * BH;
        __builtin_amdgcn_s_setprio(1);
        #pragma unroll
        for (int kk = 0; kk < 2; ++kk) {
            bf16x8 av[MI], bv[4];
            #pragma unroll
            for (int i = 0; i < MI; ++i) {
                int rr = wm + i * 16 + lr;
                int ch = (lg + 4 * kk) ^ (rr & 7);
                av[i] = *(const bf16x8*)&Ab[rr * 64 + ch * 8];
            }
            #pragma unroll
            for (int j = 0; j < 4; ++j) {
                int rr = wn + j * 16 + lr;
                int ch = (lg + 4 * kk) ^ (rr & 7);
                bv[j] = *(const bf16x8*)&Bb[rr * 64 + ch * 8];
            }
            #pragma unroll
            for (int i = 0; i < MI; ++i)
                #pragma unroll
                for (int j = 0; j < 4; ++j)
                    acc[i][j] = __builtin_amdgcn_mfma_f32_16x16x32_bf16(av[i], bv[j], acc[i][j], 0, 0, 0);
        }
        __builtin_amdgcn_s_setprio(0);
        __syncthreads();                               // drains prefetch + ends read phase
        cur ^= 1;
    }

    float*    Cf = (float*)Cv;
    ushort_t* Cb = (ushort_t*)Cv;
    float*    Pp = (EPI == EPI_PART) ? (ks ? const_cast<float*>(R) : (float*)Cv) : nullptr;
    const int rbase = lg * 4;
    #pragma unroll
    for (int i = 0; i < MI; ++i) {
        #pragma unroll
        for (int j = 0; j < 4; ++j) {
            #pragma unroll
            for (int r = 0; r < 4; ++r) {
                int row = m0 + wm + i * 16 + rbase + r;
                int col = n0 + wn + j * 16 + lr;
                size_t idx = (size_t)row * N + col;
                float v = acc[i][j][r];
                if (EPI == EPI_F32)  Cf[idx] = v;
                if (EPI == EPI_BF16) Cb[idx] = (ushort_t)f2bf1(v);
                if (EPI == EPI_GELU) Cb[idx] = (ushort_t)f2bf1(0.5f * v * (1.0f + erff(v * 0.70710678118654752f)));
                if (EPI == EPI_PART) Pp[idx] = v;
            }
        }
    }
}

// ---------------- V transpose: qkv bf16 V-slice -> vt[bh][64][T] ----------------
__global__ __launch_bounds__(256) void vprep(const ushort_t* __restrict__ qkv,
                                             ushort_t* __restrict__ vt)
{
    __shared__ ushort_t Vs[64][72];
    const int blk   = blockIdx.x;
    const int ttile = blk & 15;
    const int bh    = blk >> 4;
    const int b     = bh / H_;
    const int h     = bh % H_;
    const int tid   = threadIdx.x;
    const int t0    = ttile * 64;
    {
        const int tr = tid >> 2;
        const int dc = (tid & 3) * 16;
        const uint4* src = (const uint4*)(qkv + (size_t)(b * T_ + t0 + tr) * 2304 + 1536 + h * 64 + dc);
        uint4 v0 = src[0], v1 = src[1];
        *(uint4*)&Vs[tr][dc]     = v0;
        *(uint4*)&Vs[tr][dc + 8] = v1;
    }
    __syncthreads();
    {
        const int d  = tid >> 2;
        const int jc = (tid & 3) * 16;
        uint_t w[8];
        #pragma unroll
        for (int i = 0; i < 8; ++i)
            w[i] = (uint_t)Vs[jc + 2*i][d] | ((uint_t)Vs[jc + 2*i + 1][d] << 16);
        uint4* dst = (uint4*)(vt + ((size_t)bh * 64 + d) * T_ + t0 + jc);
        dst[0] = make_uint4(w[0], w[1], w[2], w[3]);
        dst[1] = make_uint4(w[4], w[5], w[6], w[7]);
    }
}

// ---------------- MFMA flash attention, no-LDS K/V (L2-resident), 1 wave / 16 q-rows ----------------
__global__ __launch_bounds__(64) void attn_mfma(const ushort_t* __restrict__ qkv,
    const ushort_t* __restrict__ vt, ushort_t* __restrict__ o)
{
    __shared__ ushort_t Ps[16 * 136];

    // bh-clustered XCD swizzle: 1536 blocks -> 8 chunks of 192 (3 bh each)
    int swz = (blockIdx.x & 7) * 192 + (blockIdx.x >> 3);
    const int bh  = swz >> 6;
    const int qtl = 63 - (swz & 63);     // heavy q-tiles first within chunk
    const int b   = bh / H_;
    const int h   = bh % H_;
    const int lane = threadIdx.x;
    const int l15  = lane & 15;
    const int lg   = lane >> 4;
    const int qbase = qtl * 16;
    const int qlast = qbase + 15;

    const ushort_t* qp = qkv + ((size_t)(b * T_) + qbase + l15) * 2304 + h * 64 + lg * 8;
    bf16x8 qf0 = *(const bf16x8*)qp;
    bf16x8 qf1 = *(const bf16x8*)(qp + 32);

    f32x4 od[4] = {};
    float mr[4] = {-INFINITY, -INFINITY, -INFINITY, -INFINITY};
    float lr[4] = {0.f, 0.f, 0.f, 0.f};

    const ushort_t* kbase = qkv + (size_t)(b * T_) * 2304 + 768 + h * 64;
    const ushort_t* vbase = vt + (size_t)bh * 64 * T_;
    const float SC = 0.18033688011112042f;   // 0.125 * log2(e): softmax in exp2 domain

    for (int j0 = 0; j0 <= qlast; j0 += 128) {
        f32x4 s[8];
        __builtin_amdgcn_s_setprio(1);
        #pragma unroll
        for (int n = 0; n < 8; ++n) {
            if (j0 + 16 * n <= qlast) {
                const ushort_t* kr = kbase + (size_t)(j0 + 16 * n + l15) * 2304 + lg * 8;
                bf16x8 kf0 = *(const bf16x8*)kr;
                bf16x8 kf1 = *(const bf16x8*)(kr + 32);
                f32x4 a = {};
                a = __builtin_amdgcn_mfma_f32_16x16x32_bf16(qf0, kf0, a, 0, 0, 0);
                a = __builtin_amdgcn_mfma_f32_16x16x32_bf16(qf1, kf1, a, 0, 0, 0);
                s[n] = a;
            } else {
                s[n] = f32x4{-INFINITY, -INFINITY, -INFINITY, -INFINITY};
            }
        }
        __builtin_amdgcn_s_setprio(0);

        #pragma unroll
        for (int n = 0; n < 8; ++n) {
            #pragma unroll
            for (int r = 0; r < 4; ++r) {
                float v = s[n][r] * SC;
                int jg = j0 + 16 * n + l15;
                int qg = qbase + lg * 4 + r;
                if (jg > qg) v = -INFINITY;
                s[n][r] = v;
            }
        }

        float al[4];
        #pragma unroll
        for (int r = 0; r < 4; ++r) {
            float tm = fmaxf(fmaxf(fmaxf(s[0][r], s[1][r]), fmaxf(s[2][r], s[3][r])),
                             fmaxf(fmaxf(s[4][r], s[5][r]), fmaxf(s[6][r], s[7][r])));
            tm = fmaxf(tm, __shfl_xor(tm, 1, 64));
            tm = fmaxf(tm, __shfl_xor(tm, 2, 64));
            tm = fmaxf(tm, __shfl_xor(tm, 4, 64));
            tm = fmaxf(tm, __shfl_xor(tm, 8, 64));
            float mn = fmaxf(mr[r], tm);
            al[r] = exp2f(mr[r] - mn);
            mr[r] = mn;
        }
        #pragma unroll
        for (int n = 0; n < 8; ++n)
            #pragma unroll
            for (int r = 0; r < 4; ++r)
                s[n][r] = exp2f(s[n][r] - mr[r]);
        #pragma unroll
        for (int r = 0; r < 4; ++r) {
            float ps = (s[0][r] + s[1][r]) + (s[2][r] + s[3][r]);
            ps += (s[4][r] + s[5][r]) + (s[6][r] + s[7][r]);
            ps += __shfl_xor(ps, 1, 64);
            ps += __shfl_xor(ps, 2, 64);
            ps += __shfl_xor(ps, 4, 64);
            ps += __shfl_xor(ps, 8, 64);
            lr[r] = lr[r] * al[r] + ps;
        }
        #pragma unroll
        for (int n = 0; n < 4; ++n)
            #pragma unroll
            for (int r = 0; r < 4; ++r)
                od[n][r] *= al[r];

        // P -> LDS rows (q = lg*4+r, j fast) for the PV A-fragment
        #pragma unroll
        for (int n = 0; n < 8; ++n)
            #pragma unroll
            for (int r = 0; r < 4; ++r)
                Ps[(lg * 4 + r) * 136 + 16 * n + l15] = (ushort_t)f2bf1(s[n][r]);

        __builtin_amdgcn_s_setprio(1);
        #pragma unroll
        for (int kc = 0; kc < 4; ++kc) {
            if (j0 + kc * 32 <= qlast) {
                bf16x8 pa = *(const bf16x8*)&Ps[l15 * 136 + kc * 32 + lg * 8];
                #pragma unroll
                for (int nn = 0; nn < 4; ++nn) {
                    bf16x8 vf = *(const bf16x8*)&vbase[(size_t)(16 * nn + l15) * T_ + j0 + kc * 32 + lg * 8];
                    od[nn] = __builtin_amdgcn_mfma_f32_16x16x32_bf16(pa, vf, od[nn], 0, 0, 0);
                }
            }
        }
        __builtin_amdgcn_s_setprio(0);
    }

    #pragma unroll
    for (int r = 0; r < 4; ++r) {
        float inv = 1.0f / lr[r];
        int row = qbase + lg * 4 + r;
        ushort_t* op = o + ((size_t)(b * T_ + row)) * 768 + h * 64 + l15;
        #pragma unroll
        for (int nn = 0; nn < 4; ++nn)
            op[16 * nn] = (ushort_t)f2bf1(od[nn][r] * inv);
    }
}

// ---------------- layernorm: fp32 in, bf16 out ----------------
__global__ __launch_bounds__(256) void ln_kernel(const float* __restrict__ x,
    const float* __restrict__ w, const float* __restrict__ bia, ushort_t* __restrict__ out)
{
    const int row = blockIdx.x;
    const int tid = threadIdx.x;
    const float* xr = x + (size_t)row * 768;
    float v0 = xr[tid], v1 = xr[tid + 256], v2 = xr[tid + 512];
    float s  = v0 + v1 + v2;
    float s2 = v0 * v0 + v1 * v1 + v2 * v2;
    #pragma unroll
    for (int off = 32; off > 0; off >>= 1) {
        s  += __shfl_down(s,  off, 64);
        s2 += __shfl_down(s2, off, 64);
    }
    __shared__ float sh[8];
    const int wave = tid >> 6;
    if ((tid & 63) == 0) { sh[wave] = s; sh[4 + wave] = s2; }
    __syncthreads();
    float S  = sh[0] + sh[1] + sh[2] + sh[3];
    float S2 = sh[4] + sh[5] + sh[6] + sh[7];
    float mean = S * (1.f / 768.f);
    float var  = S2 * (1.f / 768.f) - mean * mean;
    float inv  = rsqrtf(var + 1e-5f);
    ushort_t* orow = out + (size_t)row * 768;
    orow[tid]       = (ushort_t)f2bf1((v0 - mean) * inv * w[tid]       + bia[tid]);
    orow[tid + 256] = (ushort_t)f2bf1((v1 - mean) * inv * w[tid + 256] + bia[tid + 256]);
    orow[tid + 512] = (ushort_t)f2bf1((v2 - mean) * inv * w[tid + 512] + bia[tid + 512]);
}

// ---------------- fused: x += P0 + P1 ; h = LN(x) ----------------
__global__ __launch_bounds__(256) void ln_red(float* __restrict__ x,
    const float* __restrict__ P0, const float* __restrict__ P1,
    const float* __restrict__ w, const float* __restrict__ bia, ushort_t* __restrict__ out)
{
    const int row = blockIdx.x;
    const int tid = threadIdx.x;
    const size_t base = (size_t)row * 768;
    float v0 = x[base + tid]       + P0[base + tid]       + P1[base + tid];
    float v1 = x[base + tid + 256] + P0[base + tid + 256] + P1[base + tid + 256];
    float v2 = x[base + tid + 512] + P0[base + tid + 512] + P1[base + tid + 512];
    x[base + tid]       = v0;
    x[base + tid + 256] = v1;
    x[base + tid + 512] = v2;
    float s  = v0 + v1 + v2;
    float s2 = v0 * v0 + v1 * v1 + v2 * v2;
    #pragma unroll
    for (int off = 32; off > 0; off >>= 1) {
        s  += __shfl_down(s,  off, 64);
        s2 += __shfl_down(s2, off, 64);
    }
    __shared__ float sh[8];
    const int wave = tid >> 6;
    if ((tid & 63) == 0) { sh[wave] = s; sh[4 + wave] = s2; }
    __syncthreads();
    float S  = sh[0] + sh[1] + sh[2] + sh[3];
    float S2 = sh[4] + sh[5] + sh[6] + sh[7];
    float mean = S * (1.f / 768.f);
    float var  = S2 * (1.f / 768.f) - mean * mean;
    float inv  = rsqrtf(var + 1e-5f);
    ushort_t* orow = out + base;
    orow[tid]       = (ushort_t)f2bf1((v0 - mean) * inv * w[tid]       + bia[tid]);
    orow[tid + 256] = (ushort_t)f2bf1((v1 - mean) * inv * w[tid + 256] + bia[tid + 256]);
    orow[tid + 512] = (ushort_t)f2bf1((v2 - mean) * inv * w[tid + 512] + bia[tid + 512]);
}

// ---------------- embedding ----------------
__global__ __launch_bounds__(256) void embed_kernel(const int* __restrict__ ids,
    const float* __restrict__ tok, const float* __restrict__ pos, float* __restrict__ x)
{
    const int bt = blockIdx.x;
    const int t  = bt % T_;
    const int id = ids[bt];
    const int tid = threadIdx.x;
    const float* tr = tok + (size_t)id * 768;
    const float* pr = pos + (size_t)t * 768;
    float* xr = x + (size_t)bt * 768;
    xr[tid]       = tr[tid]       + pr[tid];
    xr[tid + 256] = tr[tid + 256] + pr[tid + 256];
    xr[tid + 512] = tr[tid + 512] + pr[tid + 512];
}

// ---------------- launcher ----------------
extern "C" void kernel_launch(void* const* d_in, const int* in_sizes, int n_in,
                              void* d_out, int out_size, void* d_ws, size_t ws_size,
                              hipStream_t stream)
{
    const int*   ids   = (const int*)  d_in[0];
    const float* tok   = (const float*)d_in[1];
    const float* pos   = (const float*)d_in[2];
    const float* ln1w  = (const float*)d_in[3];
    const float* ln1b  = (const float*)d_in[4];
    const float* qkvw  = (const float*)d_in[5];
    const float* outw  = (const float*)d_in[6];
    const float* ln2w  = (const float*)d_in[7];
    const float* ln2b  = (const float*)d_in[8];
    const float* upw   = (const float*)d_in[9];
    const float* downw = (const float*)d_in[10];
    const float* lnfw  = (const float*)d_in[11];
    const float* lnfb  = (const float*)d_in[12];
    float* out = (float*)d_out;

    // workspace (52.3 MB): h | x | qkv | o | vt | ffh | layerW ; tokW aliases x..end
    char* ws = (char*)d_ws;
    ushort_t* h    = (ushort_t*)ws;                               // 3,145,728 B
    float*    x    = (float*)   (ws + 3145728);                   // 6,291,456 B
    ushort_t* qkv  = (ushort_t*)(ws + 9437184);                   // 9,437,184 B
    ushort_t* o    = qkv  + (size_t)BT_ * 3 * D_;                 // 3,145,728 B
    ushort_t* vt   = o    + (size_t)BT_ * D_;                     // 3,145,728 B
    ushort_t* ffh  = vt   + (size_t)B_ * H_ * 64 * T_;            // 12,582,912 B
    ushort_t* layerW = ffh + (size_t)BT_ * FF_;                   // 14,155,776 B
    ushort_t* tokW = (ushort_t*)(ws + 3145728);                   // aliases x.. (49.15 MB)

    // split-K fp32 partials (6.29 MB each), aliasing dead regions:
    float* Pa     = (float*)(ws + 9437184);     // qkv region (dead after attn)
    float* Pb_out = (float*)ffh;                // ffh region (dead during out-proj)
    float* Pb_dwn = (float*)(ws + 18874368);    // o+vt regions (dead after out-proj)

    ushort_t* qkvwB  = layerW;
    ushort_t* outwB  = qkvwB + (size_t)3 * D_ * D_;
    ushort_t* upwB   = outwB + (size_t)D_ * D_;
    ushort_t* downwB = upwB  + (size_t)FF_ * D_;

    embed_kernel<<<BT_, 256, 0, stream>>>(ids, tok, pos, x);

    for (int l = 0; l < L_; ++l) {
        cast_layer<<<1024, 256, 0, stream>>>(
            qkvw  + (size_t)l * 3 * D_ * D_,
            outw  + (size_t)l * D_ * D_,
            upw   + (size_t)l * FF_ * D_,
            downw + (size_t)l * D_ * FF_, layerW);

        if (l == 0)
            ln_kernel<<<BT_, 256, 0, stream>>>(x, ln1w, ln1b, h);
        else
            ln_red<<<BT_, 256, 0, stream>>>(x, Pa, Pb_dwn, ln1w + l * D_, ln1b + l * D_, h);

        gemm_bt<EPI_BF16, 128, 1><<<16 * (3 * D_ / 128), 256, 0, stream>>>(
            h, qkvwB, nullptr, qkv, 3 * D_, D_, D_);

        vprep<<<B_ * H_ * (T_ / 64), 256, 0, stream>>>(qkv, vt);
        attn_mfma<<<B_ * H_ * (T_ / 16), 64, 0, stream>>>(qkv, vt, o);

        // out-proj: split-K KS=2 partials (P0 -> Pa over qkv region, P1 -> Pb_out over ffh)
        gemm_bt<EPI_PART, 64, 2><<<32 * (D_ / 128) * 2, 256, 0, stream>>>(
            o, outwB, Pb_out, Pa, D_, D_, D_ / 2);

        ln_red<<<BT_, 256, 0, stream>>>(x, Pa, Pb_out, ln2w + l * D_, ln2b + l * D_, h);

        gemm_bt<EPI_GELU, 128, 1><<<16 * (FF_ / 128), 256, 0, stream>>>(
            h, upwB, nullptr, ffh, FF_, D_, D_);

        // down-proj: split-K KS=2 partials (P0 -> Pa, P1 -> Pb_dwn over o+vt)
        gemm_bt<EPI_PART, 64, 2><<<32 * (D_ / 128) * 2, 256, 0, stream>>>(
            ffh, downwB, Pb_dwn, Pa, D_, FF_, FF_ / 2);
    }

    ln_red<<<BT_, 256, 0, stream>>>(x, Pa, Pb_dwn, lnfw, lnfb, h);
    cast_bf16<<<2048, 256, 0, stream>>>(tok, tokW, V_ * D_ / 8);

    // lm_head in 5 N-chunks of 6400 (diagnostic: surfaces per-layer hotspots in top-5)
    for (int c = 0; c < 5; ++c) {
        gemm_bt<EPI_F32, 128, 1><<<16 * 50, 256, 0, stream>>>(
            h, tokW + (size_t)c * 6400 * D_, nullptr, out + (size_t)c * 6400, V_, D_, D_);
    }
}